// Round 5
// baseline (20392.581 us; speedup 1.0000x reference)
//
#include <hip/hip_runtime.h>
#include <stdint.h>

#define T_LEN 128
#define BATCH 128
#define DHID 512
#define H 256
#define NTAGS 60
#define START_TAG 58
#define STOP_TAG 59
#define NEGV -10000.0f

typedef __attribute__((ext_vector_type(8))) short bf16x8;
typedef __attribute__((ext_vector_type(4))) short bf16x4;
typedef __attribute__((ext_vector_type(4))) float floatx4;
typedef unsigned short u16;
typedef unsigned long long u64c;

__device__ __forceinline__ u16 f2bf(float f) {
  union { float f; uint32_t u; } c; c.f = f;
  uint32_t u = c.u;
  u += 0x7FFFu + ((u >> 16) & 1u);
  return (u16)(u >> 16);
}
__device__ __forceinline__ float bf2f(u16 h) {
  union { uint32_t u; float f; } c; c.u = ((uint32_t)h) << 16;
  return c.f;
}
__device__ __forceinline__ float sigmf(float x) { return 1.0f / (1.0f + __expf(-x)); }
__device__ __forceinline__ float tanhfast(float x) {
  x = fminf(fmaxf(x, -15.0f), 15.0f);
  float e = __expf(2.0f * x);
  return (e - 1.0f) / (e + 1.0f);
}

// ---------------------------------------------------------------------------
// Pack fp32 weights -> bf16 workspace copies.
// ---------------------------------------------------------------------------
__global__ void pack_kernel(const float* __restrict__ whh1, const float* __restrict__ whh,
                            const float* __restrict__ wih, const float* __restrict__ fcw,
                            u16* __restrict__ whh_bf, u16* __restrict__ wih_bf,
                            u16* __restrict__ fcw_bf) {
  const int n_whh1 = 2 * 1024 * 256;
  const int n_whh  = 6 * 2 * 1024 * 256;
  const int n_wih  = 6 * 2 * 1024 * 512;
  const int n_fcw  = 64 * 512;
  const int total = n_whh1 + n_whh + n_wih + n_fcw;
  for (int i = blockIdx.x * blockDim.x + threadIdx.x; i < total; i += gridDim.x * blockDim.x) {
    if (i < n_whh1) {
      whh_bf[i] = f2bf(whh1[i]);
    } else if (i < n_whh1 + n_whh) {
      whh_bf[i] = f2bf(whh[i - n_whh1]);
    } else if (i < n_whh1 + n_whh + n_wih) {
      int j = i - n_whh1 - n_whh;
      wih_bf[j] = f2bf(wih[j]);
    } else {
      int j = i - n_whh1 - n_whh - n_wih;
      int row = j >> 9;
      fcw_bf[j] = (row < NTAGS) ? f2bf(fcw[j]) : (u16)0;
    }
  }
}

// ---------------------------------------------------------------------------
// Layer-1 xw, TRANSPOSED layout: xw[t][col(2048)][b(128)].
// ---------------------------------------------------------------------------
__global__ void xw1_kernel(const float* __restrict__ sent, const float* __restrict__ wih1,
                           const float* __restrict__ b1, u16* __restrict__ xw) {
  int idx = blockIdx.x * blockDim.x + threadIdx.x;
  int b = idx & 127;
  int rest = idx >> 7;
  int col = rest & 2047;
  int t = rest >> 11;
  int row = t * BATCH + b;
  const float* x = sent + row * 3;
  const float* w = wih1 + col * 3;
  float a = b1[col] + x[0] * w[0] + x[1] * w[1] + x[2] * w[2];
  xw[idx] = f2bf(a);
}

// ---------------------------------------------------------------------------
// xw GEMM layers 2..7: out transposed xw[t][col][b].
// ---------------------------------------------------------------------------
__launch_bounds__(256, 4)
__global__ void gemm_xw_kernel(const u16* __restrict__ cur, const u16* __restrict__ prev,
                               const u16* __restrict__ W, const float* __restrict__ bias,
                               u16* __restrict__ xw) {
  __shared__ __align__(16) u16 As[64][72];
  const int nbase = blockIdx.x * 256;
  const int m0 = blockIdx.y * 64;
  const int tid = threadIdx.x;
  const int wv = tid >> 6, ln = tid & 63;
  const int c16 = ln & 15, q = ln >> 4;
  const int ncol0 = nbase + wv * 64;

  floatx4 acc[4][4];
#pragma unroll
  for (int i = 0; i < 4; ++i)
#pragma unroll
    for (int j = 0; j < 4; ++j) { acc[i][j][0] = 0.f; acc[i][j][1] = 0.f; acc[i][j][2] = 0.f; acc[i][j][3] = 0.f; }

  for (int kc = 0; kc < 8; ++kc) {
    {
      int u = tid * 2;
#pragma unroll
      for (int z = 0; z < 2; ++z, ++u) {
        int r = u >> 3, cu = (u & 7) * 8;
        int gaddr = (m0 + r) * DHID + kc * 64 + cu;
        bf16x8 a8 = *(const bf16x8*)(cur + gaddr);
        u16* ap = (u16*)&a8;
        if (prev) {
          bf16x8 p8 = *(const bf16x8*)(prev + gaddr);
          u16* pp = (u16*)&p8;
#pragma unroll
          for (int e = 0; e < 8; ++e) {
            float va = (ap[e] & 0x8000) ? 0.f : bf2f(ap[e]);
            float vp = (pp[e] & 0x8000) ? 0.f : bf2f(pp[e]);
            ap[e] = f2bf(va + vp);
          }
        } else {
#pragma unroll
          for (int e = 0; e < 8; ++e) if (ap[e] & 0x8000) ap[e] = 0;
        }
        *(bf16x8*)(&As[r][cu]) = a8;
      }
    }
    __syncthreads();
#pragma unroll
    for (int kt = 0; kt < 2; ++kt) {
      int kg = kc * 64 + kt * 32 + q * 8;
      bf16x8 bfr[4];
#pragma unroll
      for (int nt = 0; nt < 4; ++nt)
        bfr[nt] = *(const bf16x8*)(W + (ncol0 + nt * 16 + c16) * DHID + kg);
      bf16x8 afr[4];
#pragma unroll
      for (int mt = 0; mt < 4; ++mt)
        afr[mt] = *(const bf16x8*)(&As[mt * 16 + c16][kt * 32 + q * 8]);
#pragma unroll
      for (int nt = 0; nt < 4; ++nt)
#pragma unroll
        for (int mt = 0; mt < 4; ++mt)
          acc[nt][mt] = __builtin_amdgcn_mfma_f32_16x16x32_bf16(afr[mt], bfr[nt], acc[nt][mt], 0, 0, 0);
    }
    __syncthreads();
  }
  const int t = m0 >> 7;
  const int bb = (m0 & 127) + q * 4;
#pragma unroll
  for (int nt = 0; nt < 4; ++nt) {
    int col = ncol0 + nt * 16 + c16;
    float bv = bias[col];
#pragma unroll
    for (int mt = 0; mt < 4; ++mt) {
      bf16x4 v;
#pragma unroll
      for (int r = 0; r < 4; ++r) v[r] = (short)f2bf(acc[nt][mt][r] + bv);
      *(bf16x4*)(xw + ((size_t)t * 2048 + col) * 128 + bb + mt * 16) = v;
    }
  }
}

// ---------------------------------------------------------------------------
// LSTM scan, multi-chain latency-hiding design. Grid: 8 blocks of 256 (4 waves).
//   blockIdx.x = dir*4 + dq.  Block owns 64 h-cols (all 4 gates) of one dir,
//   W slice LDS-resident, and time-multiplexes the 4 independent batch-chain
//   recurrences (bc=0..3, 32 batch rows each). Per round (4 chain-steps):
//     xw prefetch (all chains) -> per chain: poll flag, A-frags direct from
//     LLC (agent u64 loads), MFMA, gates -> hstage[c] -> barrier ->
//     publish all 4 chains (agent stores) -> barrier (drain) -> 4 bumps ->
//     obuf stores (off critical path).
//   Each chain's exchange RTT hides behind the other 3 chains' compute.
// ---------------------------------------------------------------------------
__launch_bounds__(256, 1)
__global__ void scan_kernel(const u16* __restrict__ whh, const u16* __restrict__ xw,
                            const float* __restrict__ h0, const float* __restrict__ c0,
                            u16* __restrict__ obuf, u16* __restrict__ hG,
                            unsigned* __restrict__ cnt) {
  __shared__ __align__(16) u16 Wl[256][268];      // 137216 B
  __shared__ __align__(16) u16 hstage[4][32][68]; //  17408 B (total 154624)
  const int dq  = blockIdx.x & 3;
  const int dir = blockIdx.x >> 2;
  const int tid = threadIdx.x;
  const int wv = tid >> 6, ln = tid & 63;
  const int c16 = ln & 15, q = ln >> 4;
  const int colb = dq * 64 + wv * 16;  // this wave's 16 h-cols (global col idx)

  // --- one-time: W slice -> LDS (gate g = wave g rows) ---
  {
    int g = tid >> 6, lc = tid & 63;
    const u16* wrow = whh + ((size_t)dir * 1024 + g * 256 + dq * 64 + lc) * H;
    for (int kk = 0; kk < 256; kk += 8)
      *(bf16x8*)(&Wl[g * 64 + lc][kk]) = *(const bf16x8*)(wrow + kk);
  }
  // --- one-time: publish h0 for all 4 chains (agent stores) ---
  {
    int bl = tid >> 3, cr = (tid & 7) * 8;
#pragma unroll
    for (int c = 0; c < 4; ++c) {
      const float* hrow = h0 + ((size_t)dir * BATCH + c * 32 + bl) * H + dq * 64 + cr;
      u16 tmp[8];
#pragma unroll
      for (int j = 0; j < 8; ++j) tmp[j] = f2bf(hrow[j]);
      u64c* src = (u64c*)tmp;
      u64c* dst = (u64c*)(hG + ((size_t)dir * BATCH + c * 32 + bl) * H + dq * 64 + cr);
      __hip_atomic_store(&dst[0], src[0], __ATOMIC_RELAXED, __HIP_MEMORY_SCOPE_AGENT);
      __hip_atomic_store(&dst[1], src[1], __ATOMIC_RELAXED, __HIP_MEMORY_SCOPE_AGENT);
    }
  }
  // --- c state for all 4 chains (fp32, registers) ---
  float creg[4][2][4];
#pragma unroll
  for (int c = 0; c < 4; ++c)
#pragma unroll
    for (int mt = 0; mt < 2; ++mt)
#pragma unroll
      for (int r = 0; r < 4; ++r)
        creg[c][mt][r] = c0[((size_t)dir * BATCH + c * 32 + mt * 16 + q * 4 + r) * H + colb + c16];

  __syncthreads();  // drains h0 publishes
  if (tid < 4)
    __hip_atomic_fetch_add(cnt + (dir * 4 + tid) * 32, 1u, __ATOMIC_RELAXED, __HIP_MEMORY_SCOPE_AGENT);

  const size_t hGhalf = (size_t)2 * BATCH * H;
  const int bl = tid >> 3, cr = (tid & 7) * 8;  // publish mapping

  for (int s = 0; s < T_LEN; ++s) {
    const int t = dir ? (T_LEN - 1 - s) : s;
    const int p = s & 1, pn = p ^ 1;
    const unsigned tgt = 4u * (unsigned)(s + 1);

    // 1) xw prefetch for all 4 chains (HBM latency overlaps polls/compute)
    bf16x4 xwv[4][4][2];  // [chain][gate][mt]
#pragma unroll
    for (int c = 0; c < 4; ++c)
#pragma unroll
      for (int g = 0; g < 4; ++g)
#pragma unroll
        for (int mt = 0; mt < 2; ++mt)
          xwv[c][g][mt] = *(const bf16x4*)(xw +
              ((size_t)t * 2048 + dir * 1024 + g * 256 + colb + c16) * 128 +
              c * 32 + mt * 16 + q * 4);

    // 2) per chain: poll -> A-frags from LLC -> MFMA -> gates -> hstage
#pragma unroll
    for (int c = 0; c < 4; ++c) {
      unsigned* grpcnt = cnt + (dir * 4 + c) * 32;
      while (__hip_atomic_load(grpcnt, __ATOMIC_RELAXED, __HIP_MEMORY_SCOPE_AGENT) < tgt)
        __builtin_amdgcn_s_sleep(1);

      bf16x8 afrag[2][8];
#pragma unroll
      for (int mt = 0; mt < 2; ++mt)
#pragma unroll
        for (int kt = 0; kt < 8; ++kt) {
          const u64c* ap = (const u64c*)(hG + p * hGhalf +
              ((size_t)dir * BATCH + c * 32 + mt * 16 + c16) * H + kt * 32 + q * 8);
          union { u64c v[2]; bf16x8 f; } u;
          u.v[0] = __hip_atomic_load(&ap[0], __ATOMIC_RELAXED, __HIP_MEMORY_SCOPE_AGENT);
          u.v[1] = __hip_atomic_load(&ap[1], __ATOMIC_RELAXED, __HIP_MEMORY_SCOPE_AGENT);
          afrag[mt][kt] = u.f;
        }

      floatx4 acc[4][2];
#pragma unroll
      for (int g = 0; g < 4; ++g)
#pragma unroll
        for (int mt = 0; mt < 2; ++mt)
#pragma unroll
          for (int r = 0; r < 4; ++r)
            acc[g][mt][r] = bf2f((u16)xwv[c][g][mt][r]);
#pragma unroll
      for (int g = 0; g < 4; ++g) {
        bf16x8 bfr[8];
#pragma unroll
        for (int kt = 0; kt < 8; ++kt)
          bfr[kt] = *(const bf16x8*)(&Wl[g * 64 + wv * 16 + c16][kt * 32 + q * 8]);
#pragma unroll
        for (int kt = 0; kt < 8; ++kt)
#pragma unroll
          for (int mt = 0; mt < 2; ++mt)
            acc[g][mt] = __builtin_amdgcn_mfma_f32_16x16x32_bf16(afrag[mt][kt], bfr[kt], acc[g][mt], 0, 0, 0);
      }
#pragma unroll
      for (int mt = 0; mt < 2; ++mt)
#pragma unroll
        for (int r = 0; r < 4; ++r) {
          float ig = sigmf(acc[0][mt][r]);
          float fg = sigmf(acc[1][mt][r]);
          float gg = tanhfast(acc[2][mt][r]);
          float og = sigmf(acc[3][mt][r]);
          float cn = fg * creg[c][mt][r] + ig * gg;
          creg[c][mt][r] = cn;
          hstage[c][mt * 16 + q * 4 + r][wv * 16 + c16] = f2bf(og * tanhfast(cn));
        }
    }
    __syncthreads();  // (a) hstage complete

    // 3) read-back + publish all 4 chains
    bf16x8 hv[4];
#pragma unroll
    for (int c = 0; c < 4; ++c) hv[c] = *(const bf16x8*)(&hstage[c][bl][cr]);
#pragma unroll
    for (int c = 0; c < 4; ++c) {
      u64c* src = (u64c*)&hv[c];
      u64c* dst = (u64c*)(hG + pn * hGhalf + ((size_t)dir * BATCH + c * 32 + bl) * H + dq * 64 + cr);
      __hip_atomic_store(&dst[0], src[0], __ATOMIC_RELAXED, __HIP_MEMORY_SCOPE_AGENT);
      __hip_atomic_store(&dst[1], src[1], __ATOMIC_RELAXED, __HIP_MEMORY_SCOPE_AGENT);
    }
    __syncthreads();  // (b) drains publishes (vmcnt(0)) before bumps
    if (tid < 4)
      __hip_atomic_fetch_add(cnt + (dir * 4 + tid) * 32, 1u, __ATOMIC_RELAXED, __HIP_MEMORY_SCOPE_AGENT);

    // 4) obuf stores (off critical path; drain at next round's barrier)
#pragma unroll
    for (int c = 0; c < 4; ++c)
      *(bf16x8*)(obuf + ((size_t)t * BATCH + c * 32 + bl) * DHID + dir * H + dq * 64 + cr) = hv[c];
  }
}

// ---------------------------------------------------------------------------
// FC: feats[16384][64] = out7[16384][512] @ fcw^T + fc_b
// ---------------------------------------------------------------------------
__launch_bounds__(256, 4)
__global__ void fc_kernel(const u16* __restrict__ A, const u16* __restrict__ W,
                          const float* __restrict__ fb, float* __restrict__ feats) {
  const int tid = threadIdx.x, wv = tid >> 6, ln = tid & 63;
  const int c16 = ln & 15, q = ln >> 4;
  const int m0 = blockIdx.x * 64 + wv * 16;
  floatx4 acc[4];
#pragma unroll
  for (int i = 0; i < 4; ++i) { acc[i][0] = 0.f; acc[i][1] = 0.f; acc[i][2] = 0.f; acc[i][3] = 0.f; }
#pragma unroll
  for (int kt = 0; kt < 16; ++kt) {
    bf16x8 a = *(const bf16x8*)(A + (m0 + c16) * DHID + kt * 32 + q * 8);
#pragma unroll
    for (int nt = 0; nt < 4; ++nt) {
      bf16x8 b = *(const bf16x8*)(W + (nt * 16 + c16) * DHID + kt * 32 + q * 8);
      acc[nt] = __builtin_amdgcn_mfma_f32_16x16x32_bf16(a, b, acc[nt], 0, 0, 0);
    }
  }
#pragma unroll
  for (int nt = 0; nt < 4; ++nt) {
    int n = nt * 16 + c16;
    if (n < NTAGS) {
      float bv = fb[n];
#pragma unroll
      for (int r = 0; r < 4; ++r)
        feats[(m0 + q * 4 + r) * 64 + n] = acc[nt][r] + bv;
    }
  }
}

// ---------------------------------------------------------------------------
// CRF: one wave per batch item.
// ---------------------------------------------------------------------------
__launch_bounds__(64, 1)
__global__ void crf_kernel(const float* __restrict__ feats, const float* __restrict__ trans,
                           const int* __restrict__ tags, float* __restrict__ out) {
  __shared__ float Tl[60][65];
  __shared__ float abuf[2][64];
  const int b = blockIdx.x;
  const int ln = threadIdx.x;
  for (int i = ln; i < 3600; i += 64) Tl[i / 60][i % 60] = trans[i];
  __syncthreads();

  float gsc = 0.f;
  for (int t = ln; t < T_LEN; t += 64) {
    int tg = tags[t * BATCH + b];
    int pv = (t == 0) ? START_TAG : tags[(t - 1) * BATCH + b];
    gsc += Tl[tg][pv] + feats[(t * BATCH + b) * 64 + tg];
  }
#pragma unroll
  for (int off = 32; off > 0; off >>= 1) gsc += __shfl_down(gsc, off);
  if (ln == 0) gsc += Tl[STOP_TAG][tags[(T_LEN - 1) * BATCH + b]];

  abuf[0][ln] = (ln == START_TAG) ? 0.f : NEGV;
  __syncthreads();
  const float* Trow = Tl[ln < NTAGS ? ln : 0];
  const int myk = (ln < NTAGS) ? ln : 0;
  for (int t = 0; t < T_LEN; ++t) {
    const int cb = t & 1, nb2 = cb ^ 1;
    float m = -1e30f;
    for (int p = 0; p < NTAGS; ++p) m = fmaxf(m, abuf[cb][p] + Trow[p]);
    float ssum = 0.f;
    for (int p = 0; p < NTAGS; ++p) ssum += __expf(abuf[cb][p] + Trow[p] - m);
    float nv = m + __logf(ssum) + feats[(t * BATCH + b) * 64 + myk];
    abuf[nb2][ln] = (ln < NTAGS) ? nv : NEGV;
    __syncthreads();
  }

  float v = (ln < NTAGS) ? (abuf[T_LEN & 1][ln] + Tl[STOP_TAG][ln]) : -1e30f;
  float mm = v;
#pragma unroll
  for (int off = 32; off > 0; off >>= 1) mm = fmaxf(mm, __shfl_down(mm, off));
  mm = __shfl(mm, 0);
  float es = __expf(v - mm);
#pragma unroll
  for (int off = 32; off > 0; off >>= 1) es += __shfl_down(es, off);
  if (ln == 0) out[b] = mm + __logf(es) - gsc;
}

// ---------------------------------------------------------------------------
extern "C" void kernel_launch(void* const* d_in, const int* in_sizes, int n_in,
                              void* d_out, int out_size, void* d_ws, size_t ws_size,
                              hipStream_t stream) {
  (void)in_sizes; (void)n_in; (void)out_size; (void)ws_size;
  const float* sent  = (const float*)d_in[0];
  const int*   tags  = (const int*)d_in[1];
  const float* wih1  = (const float*)d_in[2];
  const float* whh1  = (const float*)d_in[3];
  const float* b1    = (const float*)d_in[4];
  const float* wih   = (const float*)d_in[5];
  const float* whh   = (const float*)d_in[6];
  const float* bias  = (const float*)d_in[7];
  const float* fcw   = (const float*)d_in[8];
  const float* fcb   = (const float*)d_in[9];
  const float* h0    = (const float*)d_in[10];
  const float* c0    = (const float*)d_in[11];
  const float* trans = (const float*)d_in[12];
  float* out = (float*)d_out;

  char* ws = (char*)d_ws;
  size_t off = 0;
  auto alloc = [&](size_t bytes) -> void* {
    void* p = ws + off;
    off = (off + bytes + 255) & ~(size_t)255;
    return p;
  };
  u16* whh_bf = (u16*)alloc((size_t)7 * 2 * 1024 * 256 * 2);
  u16* wih_bf = (u16*)alloc((size_t)6 * 2 * 1024 * 512 * 2);
  u16* fcw_bf = (u16*)alloc((size_t)64 * 512 * 2);
  u16* xw     = (u16*)alloc((size_t)16384 * 2048 * 2);
  u16* ob[3];
  for (int i = 0; i < 3; ++i) ob[i] = (u16*)alloc((size_t)16384 * 512 * 2);
  float* feats = (float*)alloc((size_t)16384 * 64 * 4);
  u16* hG      = (u16*)alloc((size_t)2 * 2 * BATCH * H * 2);
  unsigned* cnt = (unsigned*)alloc((size_t)7 * 8 * 32 * 4);

  hipMemsetAsync(cnt, 0, (size_t)7 * 8 * 32 * 4, stream);

  hipLaunchKernelGGL(pack_kernel, dim3(4096), dim3(256), 0, stream,
                     whh1, whh, wih, fcw, whh_bf, wih_bf, fcw_bf);
  hipLaunchKernelGGL(xw1_kernel, dim3(131072), dim3(256), 0, stream, sent, wih1, b1, xw);
  hipLaunchKernelGGL(scan_kernel, dim3(8), dim3(256), 0, stream,
                     whh_bf, xw, h0, c0, ob[0], hG, cnt);
  for (int L = 1; L < 7; ++L) {
    const u16* curb = ob[(L - 1) % 3];
    const u16* prevb = (L >= 2) ? ob[(L - 2) % 3] : nullptr;
    hipLaunchKernelGGL(gemm_xw_kernel, dim3(8, 256), dim3(256), 0, stream,
                       curb, prevb, wih_bf + (size_t)(L - 1) * 2 * 1024 * 512,
                       bias + (size_t)(L - 1) * 2048, xw);
    hipLaunchKernelGGL(scan_kernel, dim3(8), dim3(256), 0, stream,
                       whh_bf + (size_t)L * 2 * 1024 * 256, xw,
                       h0 + (size_t)L * 2 * 128 * 256, c0 + (size_t)L * 2 * 128 * 256,
                       ob[L % 3], hG, cnt + (size_t)L * 8 * 32);
  }
  hipLaunchKernelGGL(fc_kernel, dim3(256), dim3(256), 0, stream, ob[0], fcw_bf, fcb, feats);
  hipLaunchKernelGGL(crf_kernel, dim3(128), dim3(64), 0, stream, feats, trans, tags, out);
}

// Round 6
// 4205.581 us; speedup vs baseline: 4.8489x; 4.8489x over previous
//
#include <hip/hip_runtime.h>
#include <hip/hip_fp8.h>
#include <stdint.h>

#define T_LEN 128
#define BATCH 128
#define DHID 512
#define H 256
#define NTAGS 60
#define START_TAG 58
#define STOP_TAG 59
#define NEGV -10000.0f

typedef __attribute__((ext_vector_type(8))) short bf16x8;
typedef __attribute__((ext_vector_type(4))) short bf16x4;
typedef __attribute__((ext_vector_type(4))) float floatx4;
typedef unsigned short u16;
typedef unsigned char u8;
typedef unsigned long long u64c;

__device__ __forceinline__ u16 f2bf(float f) {
  union { float f; uint32_t u; } c; c.f = f;
  uint32_t u = c.u;
  u += 0x7FFFu + ((u >> 16) & 1u);
  return (u16)(u >> 16);
}
__device__ __forceinline__ float bf2f(u16 h) {
  union { uint32_t u; float f; } c; c.u = ((uint32_t)h) << 16;
  return c.f;
}
__device__ __forceinline__ u8 ftofp8(float f) {
  __hip_fp8_e4m3 v(f);
  return (u8)v.__x;
}
__device__ __forceinline__ float fp8tof(u8 b) {
  __hip_fp8_e4m3 v; v.__x = (__hip_fp8_storage_t)b;
  return (float)v;
}
__device__ __forceinline__ float sigmf(float x) { return 1.0f / (1.0f + __expf(-x)); }
__device__ __forceinline__ float tanhfast(float x) {
  x = fminf(fmaxf(x, -15.0f), 15.0f);
  float e = __expf(2.0f * x);
  return (e - 1.0f) / (e + 1.0f);
}

// ---------------------------------------------------------------------------
// Pack weights: whh -> fp8 [7][2][1024][256]; wih -> bf16; fcw -> bf16.
// ---------------------------------------------------------------------------
__global__ void pack_kernel(const float* __restrict__ whh1, const float* __restrict__ whh,
                            const float* __restrict__ wih, const float* __restrict__ fcw,
                            u8* __restrict__ whh_f8, u16* __restrict__ wih_bf,
                            u16* __restrict__ fcw_bf) {
  const int n_whh1 = 2 * 1024 * 256;
  const int n_whh  = 6 * 2 * 1024 * 256;
  const int n_wih  = 6 * 2 * 1024 * 512;
  const int n_fcw  = 64 * 512;
  const int total = n_whh1 + n_whh + n_wih + n_fcw;
  for (int i = blockIdx.x * blockDim.x + threadIdx.x; i < total; i += gridDim.x * blockDim.x) {
    if (i < n_whh1) {
      whh_f8[i] = ftofp8(whh1[i]);
    } else if (i < n_whh1 + n_whh) {
      whh_f8[i] = ftofp8(whh[i - n_whh1]);
    } else if (i < n_whh1 + n_whh + n_wih) {
      int j = i - n_whh1 - n_whh;
      wih_bf[j] = f2bf(wih[j]);
    } else {
      int j = i - n_whh1 - n_whh - n_wih;
      int row = j >> 9;
      fcw_bf[j] = (row < NTAGS) ? f2bf(fcw[j]) : (u16)0;
    }
  }
}

// ---------------------------------------------------------------------------
// Layer-1 xw (Din=3), fp8 out, layout xw[t][col(2048)][b(128)].
// ---------------------------------------------------------------------------
__global__ void xw1_kernel(const float* __restrict__ sent, const float* __restrict__ wih1,
                           const float* __restrict__ b1, u8* __restrict__ xw) {
  int idx = blockIdx.x * blockDim.x + threadIdx.x;
  int b = idx & 127;
  int rest = idx >> 7;
  int col = rest & 2047;
  int t = rest >> 11;
  int row = t * BATCH + b;
  const float* x = sent + row * 3;
  const float* w = wih1 + col * 3;
  float a = b1[col] + x[0] * w[0] + x[1] * w[1] + x[2] * w[2];
  xw[idx] = ftofp8(a);
}

// ---------------------------------------------------------------------------
// xw GEMM layers 2..7 (bf16 MFMA), fp8 epilogue, out xw[t][col][b] fp8.
// ---------------------------------------------------------------------------
__launch_bounds__(256, 4)
__global__ void gemm_xw_kernel(const u16* __restrict__ cur, const u16* __restrict__ prev,
                               const u16* __restrict__ W, const float* __restrict__ bias,
                               u8* __restrict__ xw) {
  __shared__ __align__(16) u16 As[64][72];
  const int nbase = blockIdx.x * 256;
  const int m0 = blockIdx.y * 64;
  const int tid = threadIdx.x;
  const int wv = tid >> 6, ln = tid & 63;
  const int c16 = ln & 15, q = ln >> 4;
  const int ncol0 = nbase + wv * 64;

  floatx4 acc[4][4];
#pragma unroll
  for (int i = 0; i < 4; ++i)
#pragma unroll
    for (int j = 0; j < 4; ++j) { acc[i][j][0] = 0.f; acc[i][j][1] = 0.f; acc[i][j][2] = 0.f; acc[i][j][3] = 0.f; }

  for (int kc = 0; kc < 8; ++kc) {
    {
      int u = tid * 2;
#pragma unroll
      for (int z = 0; z < 2; ++z, ++u) {
        int r = u >> 3, cu = (u & 7) * 8;
        int gaddr = (m0 + r) * DHID + kc * 64 + cu;
        bf16x8 a8 = *(const bf16x8*)(cur + gaddr);
        u16* ap = (u16*)&a8;
        if (prev) {
          bf16x8 p8 = *(const bf16x8*)(prev + gaddr);
          u16* pp = (u16*)&p8;
#pragma unroll
          for (int e = 0; e < 8; ++e) {
            float va = (ap[e] & 0x8000) ? 0.f : bf2f(ap[e]);
            float vp = (pp[e] & 0x8000) ? 0.f : bf2f(pp[e]);
            ap[e] = f2bf(va + vp);
          }
        } else {
#pragma unroll
          for (int e = 0; e < 8; ++e) if (ap[e] & 0x8000) ap[e] = 0;
        }
        *(bf16x8*)(&As[r][cu]) = a8;
      }
    }
    __syncthreads();
#pragma unroll
    for (int kt = 0; kt < 2; ++kt) {
      int kg = kc * 64 + kt * 32 + q * 8;
      bf16x8 bfr[4];
#pragma unroll
      for (int nt = 0; nt < 4; ++nt)
        bfr[nt] = *(const bf16x8*)(W + (ncol0 + nt * 16 + c16) * DHID + kg);
      bf16x8 afr[4];
#pragma unroll
      for (int mt = 0; mt < 4; ++mt)
        afr[mt] = *(const bf16x8*)(&As[mt * 16 + c16][kt * 32 + q * 8]);
#pragma unroll
      for (int nt = 0; nt < 4; ++nt)
#pragma unroll
        for (int mt = 0; mt < 4; ++mt)
          acc[nt][mt] = __builtin_amdgcn_mfma_f32_16x16x32_bf16(afr[mt], bfr[nt], acc[nt][mt], 0, 0, 0);
    }
    __syncthreads();
  }
  const int t = m0 >> 7;
  const int bb = (m0 & 127) + q * 4;
#pragma unroll
  for (int nt = 0; nt < 4; ++nt) {
    int col = ncol0 + nt * 16 + c16;
    float bv = bias[col];
#pragma unroll
    for (int mt = 0; mt < 4; ++mt) {
      uint32_t o = 0;
#pragma unroll
      for (int r = 0; r < 4; ++r)
        ((u8*)&o)[r] = ftofp8(acc[nt][mt][r] + bv);
      *(uint32_t*)(xw + ((size_t)t * 2048 + col) * 128 + bb + mt * 16) = o;
    }
  }
}

// ---------------------------------------------------------------------------
// LSTM scan, self-contained per block (NO inter-block exchange).
// Grid: 16 blocks (dir*8 + bc), block 512 (8 waves, 2/SIMD).
// W_hh (fp8): gates i,f LDS-resident (512x264); gates g,o VGPR-resident
// (64 VGPRs/wave). h (fp8) double-buffered in LDS; one barrier per step.
// xw fp8, prefetched one step ahead. obuf bf16 via staging buffer.
// ---------------------------------------------------------------------------
__launch_bounds__(512, 2)
__global__ void scan_kernel(const u8* __restrict__ whh, const u8* __restrict__ xw,
                            const float* __restrict__ h0, const float* __restrict__ c0,
                            u16* __restrict__ obuf) {
  __shared__ __align__(16) u8 Wl[512][264];        // 135168 B
  __shared__ __align__(16) u8 hbuf[2][16][264];    //   8448 B
  __shared__ __align__(16) u16 obstage[2][16][264];//  16896 B (total 160512)
  const int bc  = blockIdx.x & 7;
  const int dir = blockIdx.x >> 3;
  const int b0  = bc * 16;
  const int tid = threadIdx.x;
  const int ln = tid & 63;
  const int wv = tid >> 6;
  const int c16 = ln & 15, q = ln >> 4;
  const int col0 = wv * 32;  // wave's 32 h-cols

  // --- W gates 0,1 (i,f) -> LDS: row tid (0..511) = g*256+col ---
  {
    const u8* wrow = whh + ((size_t)dir * 1024 + tid) * 256;
#pragma unroll
    for (int kk = 0; kk < 256; kk += 8)
      *(u64c*)(&Wl[tid][kk]) = *(const u64c*)(wrow + kk);
  }
  // --- W gates 2,3 (g,o) -> VGPR fragments ---
  long wfrag[2][2][8];  // [g-2][st][kt]
#pragma unroll
  for (int g2 = 0; g2 < 2; ++g2)
#pragma unroll
    for (int st = 0; st < 2; ++st)
#pragma unroll
      for (int kt = 0; kt < 8; ++kt)
        wfrag[g2][st][kt] = *(const long*)(whh +
            ((size_t)dir * 1024 + (g2 + 2) * 256 + col0 + st * 16 + c16) * 256 + kt * 32 + q * 8);

  // --- h0 -> hbuf[0] (fp8) ---
  {
    int row = tid >> 5, cc = (tid & 31) * 8;
    const float* hr = h0 + ((size_t)dir * BATCH + b0 + row) * H + cc;
    u8 tmp[8];
#pragma unroll
    for (int j = 0; j < 8; ++j) tmp[j] = ftofp8(hr[j]);
    *(u64c*)(&hbuf[0][row][cc]) = *(u64c*)tmp;
  }
  // --- c state (fp32 regs): batch m=q*4+r, col col0+st*16+c16 ---
  float creg[2][4];
#pragma unroll
  for (int st = 0; st < 2; ++st)
#pragma unroll
    for (int r = 0; r < 4; ++r)
      creg[st][r] = c0[((size_t)dir * BATCH + b0 + q * 4 + r) * H + col0 + st * 16 + c16];
  __syncthreads();

  // --- xw prefetch for s=0 ---
  uint32_t xwn[4][2];
  {
    const int t0 = dir ? (T_LEN - 1) : 0;
#pragma unroll
    for (int g = 0; g < 4; ++g)
#pragma unroll
      for (int st = 0; st < 2; ++st)
        xwn[g][st] = *(const uint32_t*)(xw +
            ((size_t)t0 * 2048 + dir * 1024 + g * 256 + col0 + st * 16 + c16) * 128 + b0 + q * 4);
  }

  for (int s = 0; s < T_LEN; ++s) {
    const int t = dir ? (T_LEN - 1 - s) : s;
    const int p = s & 1, pn = p ^ 1;

    uint32_t xwc[4][2];
#pragma unroll
    for (int g = 0; g < 4; ++g)
#pragma unroll
      for (int st = 0; st < 2; ++st) xwc[g][st] = xwn[g][st];
    if (s + 1 < T_LEN) {
      const int tn = dir ? (T_LEN - 2 - s) : (s + 1);
#pragma unroll
      for (int g = 0; g < 4; ++g)
#pragma unroll
        for (int st = 0; st < 2; ++st)
          xwn[g][st] = *(const uint32_t*)(xw +
              ((size_t)tn * 2048 + dir * 1024 + g * 256 + col0 + st * 16 + c16) * 128 + b0 + q * 4);
    }

    // A-frags (batch m = c16 rows, K bytes)
    long afrag[8];
#pragma unroll
    for (int kt = 0; kt < 8; ++kt)
      afrag[kt] = *(const long*)(&hbuf[p][c16][kt * 32 + q * 8]);

    // acc init from xw (fp8 -> f32)
    floatx4 acc[4][2];
#pragma unroll
    for (int g = 0; g < 4; ++g)
#pragma unroll
      for (int st = 0; st < 2; ++st)
#pragma unroll
        for (int r = 0; r < 4; ++r)
          acc[g][st][r] = fp8tof((u8)(xwc[g][st] >> (8 * r)));

    // gates 0,1 (B from LDS)
#pragma unroll
    for (int g01 = 0; g01 < 2; ++g01)
#pragma unroll
      for (int st = 0; st < 2; ++st) {
        const u8* wr = &Wl[g01 * 256 + col0 + st * 16 + c16][0];
#pragma unroll
        for (int kt = 0; kt < 8; ++kt) {
          long b = *(const long*)(wr + kt * 32 + q * 8);
          acc[g01][st] = __builtin_amdgcn_mfma_f32_16x16x32_fp8_fp8(afrag[kt], b, acc[g01][st], 0, 0, 0);
        }
      }
    // gates 2,3 (B resident in VGPRs)
#pragma unroll
    for (int g2 = 0; g2 < 2; ++g2)
#pragma unroll
      for (int st = 0; st < 2; ++st)
#pragma unroll
        for (int kt = 0; kt < 8; ++kt)
          acc[g2 + 2][st] = __builtin_amdgcn_mfma_f32_16x16x32_fp8_fp8(afrag[kt], wfrag[g2][st][kt],
                                                                       acc[g2 + 2][st], 0, 0, 0);

    // gates -> h' (fp8 into hbuf[pn], bf16 into obstage[p])
#pragma unroll
    for (int st = 0; st < 2; ++st)
#pragma unroll
      for (int r = 0; r < 4; ++r) {
        float ig = sigmf(acc[0][st][r]);
        float fg = sigmf(acc[1][st][r]);
        float gg = tanhfast(acc[2][st][r]);
        float og = sigmf(acc[3][st][r]);
        float cn = fg * creg[st][r] + ig * gg;
        creg[st][r] = cn;
        float hv = og * tanhfast(cn);
        int m = q * 4 + r, col = col0 + st * 16 + c16;
        hbuf[pn][m][col] = ftofp8(hv);
        obstage[p][m][col] = f2bf(hv);
      }
    __syncthreads();

    // obuf copy (coalesced bf16x8)
    {
      int row = tid >> 5, cc = (tid & 31) * 8;
      bf16x8 v = *(const bf16x8*)(&obstage[p][row][cc]);
      *(bf16x8*)(obuf + ((size_t)t * BATCH + b0 + row) * DHID + dir * H + cc) = v;
    }
  }
}

// ---------------------------------------------------------------------------
// FC: feats[16384][64] = out7[16384][512] @ fcw^T + fc_b
// ---------------------------------------------------------------------------
__launch_bounds__(256, 4)
__global__ void fc_kernel(const u16* __restrict__ A, const u16* __restrict__ W,
                          const float* __restrict__ fb, float* __restrict__ feats) {
  const int tid = threadIdx.x, wv = tid >> 6, ln = tid & 63;
  const int c16 = ln & 15, q = ln >> 4;
  const int m0 = blockIdx.x * 64 + wv * 16;
  floatx4 acc[4];
#pragma unroll
  for (int i = 0; i < 4; ++i) { acc[i][0] = 0.f; acc[i][1] = 0.f; acc[i][2] = 0.f; acc[i][3] = 0.f; }
#pragma unroll
  for (int kt = 0; kt < 16; ++kt) {
    bf16x8 a = *(const bf16x8*)(A + (m0 + c16) * DHID + kt * 32 + q * 8);
#pragma unroll
    for (int nt = 0; nt < 4; ++nt) {
      bf16x8 b = *(const bf16x8*)(W + (nt * 16 + c16) * DHID + kt * 32 + q * 8);
      acc[nt] = __builtin_amdgcn_mfma_f32_16x16x32_bf16(a, b, acc[nt], 0, 0, 0);
    }
  }
#pragma unroll
  for (int nt = 0; nt < 4; ++nt) {
    int n = nt * 16 + c16;
    if (n < NTAGS) {
      float bv = fb[n];
#pragma unroll
      for (int r = 0; r < 4; ++r)
        feats[(m0 + q * 4 + r) * 64 + n] = acc[nt][r] + bv;
    }
  }
}

// ---------------------------------------------------------------------------
// CRF: one wave per batch item.
// ---------------------------------------------------------------------------
__launch_bounds__(64, 1)
__global__ void crf_kernel(const float* __restrict__ feats, const float* __restrict__ trans,
                           const int* __restrict__ tags, float* __restrict__ out) {
  __shared__ float Tl[60][65];
  __shared__ float abuf[2][64];
  const int b = blockIdx.x;
  const int ln = threadIdx.x;
  for (int i = ln; i < 3600; i += 64) Tl[i / 60][i % 60] = trans[i];
  __syncthreads();

  float gsc = 0.f;
  for (int t = ln; t < T_LEN; t += 64) {
    int tg = tags[t * BATCH + b];
    int pv = (t == 0) ? START_TAG : tags[(t - 1) * BATCH + b];
    gsc += Tl[tg][pv] + feats[(t * BATCH + b) * 64 + tg];
  }
#pragma unroll
  for (int off = 32; off > 0; off >>= 1) gsc += __shfl_down(gsc, off);
  if (ln == 0) gsc += Tl[STOP_TAG][tags[(T_LEN - 1) * BATCH + b]];

  abuf[0][ln] = (ln == START_TAG) ? 0.f : NEGV;
  __syncthreads();
  const float* Trow = Tl[ln < NTAGS ? ln : 0];
  const int myk = (ln < NTAGS) ? ln : 0;
  for (int t = 0; t < T_LEN; ++t) {
    const int cb = t & 1, nb2 = cb ^ 1;
    float m = -1e30f;
    for (int p = 0; p < NTAGS; ++p) m = fmaxf(m, abuf[cb][p] + Trow[p]);
    float ssum = 0.f;
    for (int p = 0; p < NTAGS; ++p) ssum += __expf(abuf[cb][p] + Trow[p] - m);
    float nv = m + __logf(ssum) + feats[(t * BATCH + b) * 64 + myk];
    abuf[nb2][ln] = (ln < NTAGS) ? nv : NEGV;
    __syncthreads();
  }

  float v = (ln < NTAGS) ? (abuf[T_LEN & 1][ln] + Tl[STOP_TAG][ln]) : -1e30f;
  float mm = v;
#pragma unroll
  for (int off = 32; off > 0; off >>= 1) mm = fmaxf(mm, __shfl_down(mm, off));
  mm = __shfl(mm, 0);
  float es = __expf(v - mm);
#pragma unroll
  for (int off = 32; off > 0; off >>= 1) es += __shfl_down(es, off);
  if (ln == 0) out[b] = mm + __logf(es) - gsc;
}

// ---------------------------------------------------------------------------
extern "C" void kernel_launch(void* const* d_in, const int* in_sizes, int n_in,
                              void* d_out, int out_size, void* d_ws, size_t ws_size,
                              hipStream_t stream) {
  (void)in_sizes; (void)n_in; (void)out_size; (void)ws_size;
  const float* sent  = (const float*)d_in[0];
  const int*   tags  = (const int*)d_in[1];
  const float* wih1  = (const float*)d_in[2];
  const float* whh1  = (const float*)d_in[3];
  const float* b1    = (const float*)d_in[4];
  const float* wih   = (const float*)d_in[5];
  const float* whh   = (const float*)d_in[6];
  const float* bias  = (const float*)d_in[7];
  const float* fcw   = (const float*)d_in[8];
  const float* fcb   = (const float*)d_in[9];
  const float* h0    = (const float*)d_in[10];
  const float* c0    = (const float*)d_in[11];
  const float* trans = (const float*)d_in[12];
  float* out = (float*)d_out;

  char* ws = (char*)d_ws;
  size_t off = 0;
  auto alloc = [&](size_t bytes) -> void* {
    void* p = ws + off;
    off = (off + bytes + 255) & ~(size_t)255;
    return p;
  };
  u8*  whh_f8 = (u8*)alloc((size_t)7 * 2 * 1024 * 256);
  u16* wih_bf = (u16*)alloc((size_t)6 * 2 * 1024 * 512 * 2);
  u16* fcw_bf = (u16*)alloc((size_t)64 * 512 * 2);
  u8*  xw     = (u8*)alloc((size_t)16384 * 2048);
  u16* ob[3];
  for (int i = 0; i < 3; ++i) ob[i] = (u16*)alloc((size_t)16384 * 512 * 2);
  float* feats = (float*)alloc((size_t)16384 * 64 * 4);

  hipLaunchKernelGGL(pack_kernel, dim3(4096), dim3(256), 0, stream,
                     whh1, whh, wih, fcw, whh_f8, wih_bf, fcw_bf);
  hipLaunchKernelGGL(xw1_kernel, dim3(131072), dim3(256), 0, stream, sent, wih1, b1, xw);
  hipLaunchKernelGGL(scan_kernel, dim3(16), dim3(512), 0, stream,
                     whh_f8, xw, h0, c0, ob[0]);
  for (int L = 1; L < 7; ++L) {
    const u16* curb = ob[(L - 1) % 3];
    const u16* prevb = (L >= 2) ? ob[(L - 2) % 3] : nullptr;
    hipLaunchKernelGGL(gemm_xw_kernel, dim3(8, 256), dim3(256), 0, stream,
                       curb, prevb, wih_bf + (size_t)(L - 1) * 2 * 1024 * 512,
                       bias + (size_t)(L - 1) * 2048, xw);
    hipLaunchKernelGGL(scan_kernel, dim3(16), dim3(512), 0, stream,
                       whh_f8 + (size_t)L * 2 * 1024 * 256, xw,
                       h0 + (size_t)L * 2 * 128 * 256, c0 + (size_t)L * 2 * 128 * 256,
                       ob[L % 3]);
  }
  hipLaunchKernelGGL(fc_kernel, dim3(256), dim3(256), 0, stream, ob[0], fcw_bf, fcb, feats);
  hipLaunchKernelGGL(crf_kernel, dim3(128), dim3(64), 0, stream, feats, trans, tags, out);
}

// Round 8
// 2626.304 us; speedup vs baseline: 7.7647x; 1.6013x over previous
//
#include <hip/hip_runtime.h>
#include <stdint.h>

#define T_LEN 128
#define BATCH 128
#define DHID 512
#define H 256
#define NTAGS 60
#define START_TAG 58
#define STOP_TAG 59
#define NEGV -10000.0f

typedef __attribute__((ext_vector_type(8))) short bf16x8;
typedef __attribute__((ext_vector_type(4))) short bf16x4;
typedef __attribute__((ext_vector_type(4))) float floatx4;
typedef __attribute__((ext_vector_type(2))) float floatx2;
typedef unsigned short u16;
typedef unsigned char u8;
typedef unsigned long long u64c;

__device__ __forceinline__ u16 f2bf(float f) {
  union { float f; uint32_t u; } c; c.f = f;
  uint32_t u = c.u;
  u += 0x7FFFu + ((u >> 16) & 1u);
  return (u16)(u >> 16);
}
__device__ __forceinline__ float bf2f(u16 h) {
  union { uint32_t u; float f; } c; c.u = ((uint32_t)h) << 16;
  return c.f;
}
// HW fp8 (e4m3) conversions (word-select must be a literal constant)
__device__ __forceinline__ floatx4 f8x4tof(uint32_t v) {
  floatx2 lo = __builtin_amdgcn_cvt_pk_f32_fp8((int)v, false);
  floatx2 hi = __builtin_amdgcn_cvt_pk_f32_fp8((int)v, true);
  floatx4 r;
  r[0] = lo[0]; r[1] = lo[1]; r[2] = hi[0]; r[3] = hi[1];
  return r;
}
__device__ __forceinline__ u8 ftof8(float f) {
  return (u8)(__builtin_amdgcn_cvt_pk_fp8_f32(f, f, 0, false) & 0xff);
}
__device__ __forceinline__ uint32_t pk4f8(float a, float b, float c, float d) {
  int o = __builtin_amdgcn_cvt_pk_fp8_f32(a, b, 0, false);
  o = __builtin_amdgcn_cvt_pk_fp8_f32(c, d, o, true);
  return (uint32_t)o;
}
__device__ __forceinline__ float sigx(float x) {
  float e = __expf(-x);
  return __builtin_amdgcn_rcpf(1.0f + e);
}
__device__ __forceinline__ float tanhx(float x) {
  float e = __expf(-2.0f * x);
  return 2.0f * __builtin_amdgcn_rcpf(1.0f + e) - 1.0f;
}

// ---------------------------------------------------------------------------
// Pack weights: whh -> fp8 [7][2][1024][256]; wih -> bf16; fcw -> bf16.
// ---------------------------------------------------------------------------
__global__ void pack_kernel(const float* __restrict__ whh1, const float* __restrict__ whh,
                            const float* __restrict__ wih, const float* __restrict__ fcw,
                            u8* __restrict__ whh_f8, u16* __restrict__ wih_bf,
                            u16* __restrict__ fcw_bf) {
  const int n_whh1 = 2 * 1024 * 256;
  const int n_whh  = 6 * 2 * 1024 * 256;
  const int n_wih  = 6 * 2 * 1024 * 512;
  const int n_fcw  = 64 * 512;
  const int total = n_whh1 + n_whh + n_wih + n_fcw;
  for (int i = blockIdx.x * blockDim.x + threadIdx.x; i < total; i += gridDim.x * blockDim.x) {
    if (i < n_whh1) {
      whh_f8[i] = ftof8(whh1[i]);
    } else if (i < n_whh1 + n_whh) {
      whh_f8[i] = ftof8(whh[i - n_whh1]);
    } else if (i < n_whh1 + n_whh + n_wih) {
      int j = i - n_whh1 - n_whh;
      wih_bf[j] = f2bf(wih[j]);
    } else {
      int j = i - n_whh1 - n_whh - n_wih;
      int row = j >> 9;
      fcw_bf[j] = (row < NTAGS) ? f2bf(fcw[j]) : (u16)0;
    }
  }
}

// ---------------------------------------------------------------------------
// Layer-1 xw (Din=3), fp8, layout xw[bc][t][col(2048)][16].
// One thread per uint32 (4 batch lanes): u = ((bc*128+t)*2048+col)*4 + qq.
// ---------------------------------------------------------------------------
__global__ void xw1_kernel(const float* __restrict__ sent, const float* __restrict__ wih1,
                           const float* __restrict__ b1, u8* __restrict__ xw) {
  int u = blockIdx.x * blockDim.x + threadIdx.x;
  int qq = u & 3;
  int col = (u >> 2) & 2047;
  int t = (u >> 13) & 127;
  int bc = u >> 20;
  const float* w = wih1 + col * 3;
  float w0 = w[0], w1 = w[1], w2 = w[2], bv = b1[col];
  float o[4];
#pragma unroll
  for (int j = 0; j < 4; ++j) {
    int b = bc * 16 + qq * 4 + j;
    const float* x = sent + (t * BATCH + b) * 3;
    o[j] = bv + x[0] * w0 + x[1] * w1 + x[2] * w2;
  }
  *(uint32_t*)(xw + (size_t)u * 4) = pk4f8(o[0], o[1], o[2], o[3]);
}

// ---------------------------------------------------------------------------
// xw GEMM layers 2..7 (bf16 MFMA), fp8 epilogue to xw[bc][t][col][16].
// ---------------------------------------------------------------------------
__launch_bounds__(256, 4)
__global__ void gemm_xw_kernel(const u16* __restrict__ cur, const u16* __restrict__ prev,
                               const u16* __restrict__ W, const float* __restrict__ bias,
                               u8* __restrict__ xw) {
  __shared__ __align__(16) u16 As[64][72];
  const int nbase = blockIdx.x * 256;
  const int m0 = blockIdx.y * 64;
  const int tid = threadIdx.x;
  const int wv = tid >> 6, ln = tid & 63;
  const int c16 = ln & 15, q = ln >> 4;
  const int ncol0 = nbase + wv * 64;

  floatx4 acc[4][4];
#pragma unroll
  for (int i = 0; i < 4; ++i)
#pragma unroll
    for (int j = 0; j < 4; ++j) { acc[i][j][0] = 0.f; acc[i][j][1] = 0.f; acc[i][j][2] = 0.f; acc[i][j][3] = 0.f; }

  for (int kc = 0; kc < 8; ++kc) {
    {
      int u = tid * 2;
#pragma unroll
      for (int z = 0; z < 2; ++z, ++u) {
        int r = u >> 3, cu = (u & 7) * 8;
        int gaddr = (m0 + r) * DHID + kc * 64 + cu;
        bf16x8 a8 = *(const bf16x8*)(cur + gaddr);
        u16* ap = (u16*)&a8;
        if (prev) {
          bf16x8 p8 = *(const bf16x8*)(prev + gaddr);
          u16* pp = (u16*)&p8;
#pragma unroll
          for (int e = 0; e < 8; ++e) {
            float va = (ap[e] & 0x8000) ? 0.f : bf2f(ap[e]);
            float vp = (pp[e] & 0x8000) ? 0.f : bf2f(pp[e]);
            ap[e] = f2bf(va + vp);
          }
        } else {
#pragma unroll
          for (int e = 0; e < 8; ++e) if (ap[e] & 0x8000) ap[e] = 0;
        }
        *(bf16x8*)(&As[r][cu]) = a8;
      }
    }
    __syncthreads();
#pragma unroll
    for (int kt = 0; kt < 2; ++kt) {
      int kg = kc * 64 + kt * 32 + q * 8;
      bf16x8 bfr[4];
#pragma unroll
      for (int nt = 0; nt < 4; ++nt)
        bfr[nt] = *(const bf16x8*)(W + (ncol0 + nt * 16 + c16) * DHID + kg);
      bf16x8 afr[4];
#pragma unroll
      for (int mt = 0; mt < 4; ++mt)
        afr[mt] = *(const bf16x8*)(&As[mt * 16 + c16][kt * 32 + q * 8]);
#pragma unroll
      for (int nt = 0; nt < 4; ++nt)
#pragma unroll
        for (int mt = 0; mt < 4; ++mt)
          acc[nt][mt] = __builtin_amdgcn_mfma_f32_16x16x32_bf16(afr[mt], bfr[nt], acc[nt][mt], 0, 0, 0);
    }
    __syncthreads();
  }
  const int t = m0 >> 7;
  const int bc0 = (m0 & 127) >> 4;
#pragma unroll
  for (int nt = 0; nt < 4; ++nt) {
    int col = ncol0 + nt * 16 + c16;
    float bv = bias[col];
#pragma unroll
    for (int mt = 0; mt < 4; ++mt) {
      uint32_t o = pk4f8(acc[nt][mt][0] + bv, acc[nt][mt][1] + bv,
                         acc[nt][mt][2] + bv, acc[nt][mt][3] + bv);
      *(uint32_t*)(xw + (((size_t)(bc0 + mt) * T_LEN + t) * 2048 + col) * 16 + q * 4) = o;
    }
  }
}

// ---------------------------------------------------------------------------
// LSTM scan, self-contained per block. Grid: 16 blocks (dir*8+bc), block 512.
// ALL W_hh (fp8) VGPR-resident (128 VGPRs/wave). h (fp8) double-buffered in
// LDS; one barrier per step. xw fp8 [bc][t][col][16] (coalesced, exact-fetch),
// prefetched one step ahead. HW fp8 cvt + rcp-based activations.
// ---------------------------------------------------------------------------
__launch_bounds__(512, 1)
__global__ void scan_kernel(const u8* __restrict__ whh, const u8* __restrict__ xw,
                            const float* __restrict__ h0, const float* __restrict__ c0,
                            u16* __restrict__ obuf) {
  __shared__ __align__(16) u8 hbuf[2][16][264];
  __shared__ __align__(16) u16 obstage[2][16][264];
  const int bc  = blockIdx.x & 7;
  const int dir = blockIdx.x >> 3;
  const int b0  = bc * 16;
  const int tid = threadIdx.x;
  const int ln = tid & 63;
  const int wv = tid >> 6;
  const int c16 = ln & 15, q = ln >> 4;
  const int col0 = wv * 32;

  // --- all 4 gates of W -> VGPR fragments: [g][st][kt] ---
  long wfrag[4][2][8];
#pragma unroll
  for (int g = 0; g < 4; ++g)
#pragma unroll
    for (int st = 0; st < 2; ++st)
#pragma unroll
      for (int kt = 0; kt < 8; ++kt)
        wfrag[g][st][kt] = *(const long*)(whh +
            ((size_t)dir * 1024 + g * 256 + col0 + st * 16 + c16) * 256 + kt * 32 + q * 8);

  // --- h0 -> hbuf[0] (fp8, HW pack) ---
  {
    int row = tid >> 5, cc = (tid & 31) * 8;
    const float* hr = h0 + ((size_t)dir * BATCH + b0 + row) * H + cc;
    uint32_t lo = pk4f8(hr[0], hr[1], hr[2], hr[3]);
    uint32_t hi = pk4f8(hr[4], hr[5], hr[6], hr[7]);
    *(uint32_t*)(&hbuf[0][row][cc]) = lo;
    *(uint32_t*)(&hbuf[0][row][cc + 4]) = hi;
  }
  // --- c state ---
  float creg[2][4];
#pragma unroll
  for (int st = 0; st < 2; ++st)
#pragma unroll
    for (int r = 0; r < 4; ++r)
      creg[st][r] = c0[((size_t)dir * BATCH + b0 + q * 4 + r) * H + col0 + st * 16 + c16];
  __syncthreads();

  // per-lane constant xw byte offsets; time part via pointer stepping
  const u8* xwt = xw + ((size_t)bc * T_LEN + (dir ? T_LEN - 1 : 0)) * 2048 * 16;
  const ptrdiff_t xstep = (dir ? -1 : 1) * (ptrdiff_t)(2048 * 16);
  int xoff[4][2];
#pragma unroll
  for (int g = 0; g < 4; ++g)
#pragma unroll
    for (int st = 0; st < 2; ++st)
      xoff[g][st] = (dir * 1024 + g * 256 + col0 + st * 16 + c16) * 16 + q * 4;

  u16* obt = obuf + ((size_t)(dir ? T_LEN - 1 : 0) * BATCH) * DHID;
  const ptrdiff_t ostep = (dir ? -1 : 1) * (ptrdiff_t)(BATCH * DHID);

  // prefetch s=0
  uint32_t xwn[4][2];
#pragma unroll
  for (int g = 0; g < 4; ++g)
#pragma unroll
    for (int st = 0; st < 2; ++st)
      xwn[g][st] = *(const uint32_t*)(xwt + xoff[g][st]);

  for (int s = 0; s < T_LEN; ++s) {
    const int p = s & 1, pn = p ^ 1;

    // acc init from xw (HW packed fp8->f32), consuming xwn
    floatx4 acc[4][2];
#pragma unroll
    for (int g = 0; g < 4; ++g)
#pragma unroll
      for (int st = 0; st < 2; ++st)
        acc[g][st] = f8x4tof(xwn[g][st]);

    // prefetch next step's xw
    if (s + 1 < T_LEN) {
      const u8* xn = xwt + xstep;
#pragma unroll
      for (int g = 0; g < 4; ++g)
#pragma unroll
        for (int st = 0; st < 2; ++st)
          xwn[g][st] = *(const uint32_t*)(xn + xoff[g][st]);
    }

    // A-frags from hbuf[p]
    long afrag[8];
#pragma unroll
    for (int kt = 0; kt < 8; ++kt)
      afrag[kt] = *(const long*)(&hbuf[p][c16][kt * 32 + q * 8]);

    // MFMA (all B operands VGPR-resident)
#pragma unroll
    for (int g = 0; g < 4; ++g)
#pragma unroll
      for (int st = 0; st < 2; ++st)
#pragma unroll
        for (int kt = 0; kt < 8; ++kt)
          acc[g][st] = __builtin_amdgcn_mfma_f32_16x16x32_fp8_fp8(afrag[kt], wfrag[g][st][kt],
                                                                  acc[g][st], 0, 0, 0);

    // gates -> h'
#pragma unroll
    for (int st = 0; st < 2; ++st)
#pragma unroll
      for (int r = 0; r < 4; ++r) {
        float ig = sigx(acc[0][st][r]);
        float fg = sigx(acc[1][st][r]);
        float gg = tanhx(acc[2][st][r]);
        float og = sigx(acc[3][st][r]);
        float cn = fg * creg[st][r] + ig * gg;
        creg[st][r] = cn;
        float hv = og * tanhx(cn);
        int m = q * 4 + r, col = col0 + st * 16 + c16;
        hbuf[pn][m][col] = ftof8(hv);
        obstage[p][m][col] = f2bf(hv);
      }
    __syncthreads();

    // obuf copy (coalesced 16-B)
    {
      int row = tid >> 5, cc = (tid & 31) * 8;
      bf16x8 v = *(const bf16x8*)(&obstage[p][row][cc]);
      *(bf16x8*)(obt + ((size_t)(b0 + row)) * DHID + dir * H + cc) = v;
    }
    xwt += xstep;
    obt += ostep;
  }
}

// ---------------------------------------------------------------------------
// FC: feats[16384][64] = out7[16384][512] @ fcw^T + fc_b
// ---------------------------------------------------------------------------
__launch_bounds__(256, 4)
__global__ void fc_kernel(const u16* __restrict__ A, const u16* __restrict__ W,
                          const float* __restrict__ fb, float* __restrict__ feats) {
  const int tid = threadIdx.x, wv = tid >> 6, ln = tid & 63;
  const int c16 = ln & 15, q = ln >> 4;
  const int m0 = blockIdx.x * 64 + wv * 16;
  floatx4 acc[4];
#pragma unroll
  for (int i = 0; i < 4; ++i) { acc[i][0] = 0.f; acc[i][1] = 0.f; acc[i][2] = 0.f; acc[i][3] = 0.f; }
#pragma unroll
  for (int kt = 0; kt < 16; ++kt) {
    bf16x8 a = *(const bf16x8*)(A + (m0 + c16) * DHID + kt * 32 + q * 8);
#pragma unroll
    for (int nt = 0; nt < 4; ++nt) {
      bf16x8 b = *(const bf16x8*)(W + (nt * 16 + c16) * DHID + kt * 32 + q * 8);
      acc[nt] = __builtin_amdgcn_mfma_f32_16x16x32_bf16(a, b, acc[nt], 0, 0, 0);
    }
  }
#pragma unroll
  for (int nt = 0; nt < 4; ++nt) {
    int n = nt * 16 + c16;
    if (n < NTAGS) {
      float bv = fb[n];
#pragma unroll
      for (int r = 0; r < 4; ++r)
        feats[(m0 + q * 4 + r) * 64 + n] = acc[nt][r] + bv;
    }
  }
}

// ---------------------------------------------------------------------------
// CRF: one wave per batch item.
// ---------------------------------------------------------------------------
__launch_bounds__(64, 1)
__global__ void crf_kernel(const float* __restrict__ feats, const float* __restrict__ trans,
                           const int* __restrict__ tags, float* __restrict__ out) {
  __shared__ float Tl[60][65];
  __shared__ float abuf[2][64];
  const int b = blockIdx.x;
  const int ln = threadIdx.x;
  for (int i = ln; i < 3600; i += 64) Tl[i / 60][i % 60] = trans[i];
  __syncthreads();

  float gsc = 0.f;
  for (int t = ln; t < T_LEN; t += 64) {
    int tg = tags[t * BATCH + b];
    int pv = (t == 0) ? START_TAG : tags[(t - 1) * BATCH + b];
    gsc += Tl[tg][pv] + feats[(t * BATCH + b) * 64 + tg];
  }
#pragma unroll
  for (int off = 32; off > 0; off >>= 1) gsc += __shfl_down(gsc, off);
  if (ln == 0) gsc += Tl[STOP_TAG][tags[(T_LEN - 1) * BATCH + b]];

  abuf[0][ln] = (ln == START_TAG) ? 0.f : NEGV;
  __syncthreads();
  const float* Trow = Tl[ln < NTAGS ? ln : 0];
  const int myk = (ln < NTAGS) ? ln : 0;
  for (int t = 0; t < T_LEN; ++t) {
    const int cb = t & 1, nb2 = cb ^ 1;
    float m = -1e30f;
    for (int p = 0; p < NTAGS; ++p) m = fmaxf(m, abuf[cb][p] + Trow[p]);
    float ssum = 0.f;
    for (int p = 0; p < NTAGS; ++p) ssum += __expf(abuf[cb][p] + Trow[p] - m);
    float nv = m + __logf(ssum) + feats[(t * BATCH + b) * 64 + myk];
    abuf[nb2][ln] = (ln < NTAGS) ? nv : NEGV;
    __syncthreads();
  }

  float v = (ln < NTAGS) ? (abuf[T_LEN & 1][ln] + Tl[STOP_TAG][ln]) : -1e30f;
  float mm = v;
#pragma unroll
  for (int off = 32; off > 0; off >>= 1) mm = fmaxf(mm, __shfl_down(mm, off));
  mm = __shfl(mm, 0);
  float es = __expf(v - mm);
#pragma unroll
  for (int off = 32; off > 0; off >>= 1) es += __shfl_down(es, off);
  if (ln == 0) out[b] = mm + __logf(es) - gsc;
}

// ---------------------------------------------------------------------------
extern "C" void kernel_launch(void* const* d_in, const int* in_sizes, int n_in,
                              void* d_out, int out_size, void* d_ws, size_t ws_size,
                              hipStream_t stream) {
  (void)in_sizes; (void)n_in; (void)out_size; (void)ws_size;
  const float* sent  = (const float*)d_in[0];
  const int*   tags  = (const int*)d_in[1];
  const float* wih1  = (const float*)d_in[2];
  const float* whh1  = (const float*)d_in[3];
  const float* b1    = (const float*)d_in[4];
  const float* wih   = (const float*)d_in[5];
  const float* whh   = (const float*)d_in[6];
  const float* bias  = (const float*)d_in[7];
  const float* fcw   = (const float*)d_in[8];
  const float* fcb   = (const float*)d_in[9];
  const float* h0    = (const float*)d_in[10];
  const float* c0    = (const float*)d_in[11];
  const float* trans = (const float*)d_in[12];
  float* out = (float*)d_out;

  char* ws = (char*)d_ws;
  size_t off = 0;
  auto alloc = [&](size_t bytes) -> void* {
    void* p = ws + off;
    off = (off + bytes + 255) & ~(size_t)255;
    return p;
  };
  u8*  whh_f8 = (u8*)alloc((size_t)7 * 2 * 1024 * 256);
  u16* wih_bf = (u16*)alloc((size_t)6 * 2 * 1024 * 512 * 2);
  u16* fcw_bf = (u16*)alloc((size_t)64 * 512 * 2);
  u8*  xw     = (u8*)alloc((size_t)16384 * 2048);
  u16* ob[3];
  for (int i = 0; i < 3; ++i) ob[i] = (u16*)alloc((size_t)16384 * 512 * 2);
  float* feats = (float*)alloc((size_t)16384 * 64 * 4);

  hipLaunchKernelGGL(pack_kernel, dim3(4096), dim3(256), 0, stream,
                     whh1, whh, wih, fcw, whh_f8, wih_bf, fcw_bf);
  hipLaunchKernelGGL(xw1_kernel, dim3(32768), dim3(256), 0, stream, sent, wih1, b1, xw);
  hipLaunchKernelGGL(scan_kernel, dim3(16), dim3(512), 0, stream,
                     whh_f8, xw, h0, c0, ob[0]);
  for (int L = 1; L < 7; ++L) {
    const u16* curb = ob[(L - 1) % 3];
    const u16* prevb = (L >= 2) ? ob[(L - 2) % 3] : nullptr;
    hipLaunchKernelGGL(gemm_xw_kernel, dim3(8, 256), dim3(256), 0, stream,
                       curb, prevb, wih_bf + (size_t)(L - 1) * 2 * 1024 * 512,
                       bias + (size_t)(L - 1) * 2048, xw);
    hipLaunchKernelGGL(scan_kernel, dim3(16), dim3(512), 0, stream,
                       whh_f8 + (size_t)L * 2 * 1024 * 256, xw,
                       h0 + (size_t)L * 2 * 128 * 256, c0 + (size_t)L * 2 * 128 * 256,
                       ob[L % 3]);
  }
  hipLaunchKernelGGL(fc_kernel, dim3(256), dim3(256), 0, stream, ob[0], fcw_bf, fcb, feats);
  hipLaunchKernelGGL(crf_kernel, dim3(128), dim3(64), 0, stream, feats, trans, tags, out);
}